// Round 8
// baseline (4496.772 us; speedup 1.0000x reference)
//
#include <hip/hip_runtime.h>

#define ROWS 32768      // B*T
#define D 512
#define NCODES 8192
#define NSPLIT 4
#define CODES_PER_SPLIT (NCODES / NSPLIT)   // 2048
#define BM 128          // rows per block = 8 waves * 16
#define BN 256          // codes per tile (4 per lane)
#define BKK 32          // k per stage
#define KC 384          // OpenBLAS sgemm kc panel split (verified exact, rounds 4-7)

// compile-time float4 component select (loops fully unrolled)
__device__ __forceinline__ float f4c(const float4& v, int c) {
    return c == 0 ? v.x : (c == 1 ? v.y : (c == 2 ? v.z : v.w));
}

// numpy pairwise f32 sum of squares of a 512-float row (verified exact).
__device__ __forceinline__ float np_sumsq_512(const float* __restrict__ p) {
    float blk[4];
#pragma unroll
    for (int b = 0; b < 4; ++b) {
        const float* q = p + b * 128;
        float r[8];
#pragma unroll
        for (int j = 0; j < 8; ++j) r[j] = __fmul_rn(q[j], q[j]);
#pragma unroll
        for (int i = 1; i < 16; ++i)
#pragma unroll
            for (int j = 0; j < 8; ++j)
                r[j] = __fadd_rn(r[j], __fmul_rn(q[i * 8 + j], q[i * 8 + j]));
        blk[b] = __fadd_rn(__fadd_rn(__fadd_rn(r[0], r[1]), __fadd_rn(r[2], r[3])),
                           __fadd_rn(__fadd_rn(r[4], r[5]), __fadd_rn(r[6], r[7])));
    }
    return __fadd_rn(__fadd_rn(blk[0], blk[1]), __fadd_rn(blk[2], blk[3]));
}

// ---------------- kernel 1: row sums of squares ----------------
__global__ void k_rowsums(const float* __restrict__ zE, const float* __restrict__ cb,
                          float* __restrict__ sq, float* __restrict__ e2) {
    int row = blockIdx.x * 64 + threadIdx.x;
    if (row < ROWS) {
        sq[row] = np_sumsq_512(zE + (size_t)row * D);
    } else {
        e2[row - ROWS] = np_sumsq_512(cb + (size_t)(row - ROWS) * D);
    }
}

// ---------------- kernel 2: distance GEMM + fused partial argmin ----------------
// 512 thr = 8 waves; wave owns 16 rows (uniform -> A via s_load/SGPR, zero LDS);
// lane owns 4 codes; B is the only LDS traffic: 1 ds_read_b128 per 64 FMA insts.
// B staged via 4x4 register transpose -> all-b128 conflict-free writes.
// Numerics per (row,code): m = fl(chain(k=0..383) + chain(k=384..511)),
// sequential ascending-k FMA; dist = fl(fl(s-2m)+e2). Bit-exact (rounds 4-7).
__global__ __launch_bounds__(512, 1)
void k_argmin(const float* __restrict__ zE, const float* __restrict__ cb,
              const float* __restrict__ sq, const float* __restrict__ e2,
              uint2* __restrict__ part) {
    __shared__ float Bs[BKK][BN];       // [k][code] 32 KiB

    const int cs      = blockIdx.x;
    const int rowBase = blockIdx.y * BM;
    const int tid     = threadIdx.x;
    const int lane    = tid & 63;
    // wave's 16-row offset, forced wave-uniform so A loads scalarize (s_load)
    const int wrow    = __builtin_amdgcn_readfirstlane((tid >> 6) * 16);
    const int scg4    = (tid & 63) * 4;      // staging: 4 codes
    const int sk0     = (tid >> 6) * 4;      // staging: 4 k's

    // uniform scalar loads -> SGPRs
    float srow[16];
#pragma unroll
    for (int i = 0; i < 16; ++i) srow[i] = sq[rowBase + wrow + i];

    float bvr = INFINITY;   // running best (row = lane) across tiles
    int   bir = 0;

    for (int ct = 0; ct < CODES_PER_SPLIT / BN; ++ct) {   // 8 code tiles
        const int codeBase = cs * CODES_PER_SPLIT + ct * BN;
        float acc[16][4], m1[16][4];
#pragma unroll
        for (int i = 0; i < 16; ++i)
#pragma unroll
            for (int j = 0; j < 4; ++j) { acc[i][j] = 0.0f; m1[i][j] = 0.0f; }

#pragma unroll 1
        for (int ks = 0; ks < D / BKK; ++ks) {            // 16 K stages, k ascending
            __syncthreads();
            {   // stage B: 4 codes x 4 k register transpose, all b128
                const float* g = cb + (size_t)(codeBase + scg4) * D + ks * BKK + sk0;
                float4 r0 = *(const float4*)(g);
                float4 r1 = *(const float4*)(g + D);
                float4 r2 = *(const float4*)(g + 2 * D);
                float4 r3 = *(const float4*)(g + 3 * D);
#pragma unroll
                for (int j = 0; j < 4; ++j) {
                    float4 w;
                    w.x = f4c(r0, j); w.y = f4c(r1, j);
                    w.z = f4c(r2, j); w.w = f4c(r3, j);
                    *(float4*)&Bs[sk0 + j][scg4] = w;
                }
            }
            __syncthreads();
#pragma unroll 1
            for (int kg = 0; kg < BKK / 4; ++kg) {        // 8 k-groups of 4
                float4 a4[16];                             // uniform -> s_load_dwordx4
#pragma unroll
                for (int i = 0; i < 16; ++i)
                    a4[i] = *(const float4*)(zE + (size_t)(rowBase + wrow + i) * D
                                             + ks * BKK + kg * 4);
#pragma unroll
                for (int kk = 0; kk < 4; ++kk) {
                    float4 b = *(const float4*)&Bs[kg * 4 + kk][lane * 4];
                    float bw[4] = {b.x, b.y, b.z, b.w};
#pragma unroll
                    for (int i = 0; i < 16; ++i) {
                        float a = f4c(a4[i], kk);
#pragma unroll
                        for (int j = 0; j < 4; ++j)
                            acc[i][j] = __builtin_fmaf(a, bw[j], acc[i][j]);
                    }
                }
            }
            if (ks == KC / BKK - 1) {                     // close panel 1 (k=0..383)
#pragma unroll
                for (int i = 0; i < 16; ++i)
#pragma unroll
                    for (int j = 0; j < 4; ++j) { m1[i][j] = acc[i][j]; acc[i][j] = 0.0f; }
            }
        }

        // finalize: dist = fl(fl(s - 2*fl(S1+S2)) + e2); ascending code order
        float4 e4 = *(const float4*)(e2 + codeBase + lane * 4);
        float ec[4] = {e4.x, e4.y, e4.z, e4.w};
#pragma unroll
        for (int i = 0; i < 16; ++i) {
            float v = INFINITY;
            int   x = 0;
#pragma unroll
            for (int j = 0; j < 4; ++j) {
                float m = __fadd_rn(m1[i][j], acc[i][j]);
                float d = __fadd_rn(__fsub_rn(srow[i], __fmul_rn(2.0f, m)), ec[j]);
                if (d < v) { v = d; x = codeBase + lane * 4 + j; }
            }
            // wave-level lexicographic (val, idx) reduce
#pragma unroll
            for (int off = 32; off; off >>= 1) {
                float v2 = __shfl_xor(v, off);
                int   x2 = __shfl_xor(x, off);
                if (v2 < v || (v2 == v && x2 < x)) { v = v2; x = x2; }
            }
            if (lane == i) {                              // row i lives in lane i
                if (v < bvr || (v == bvr && x < bir)) { bvr = v; bir = x; }
            }
        }
    }

    if (lane < 16)
        part[(size_t)(rowBase + wrow + lane) * NSPLIT + cs] =
            make_uint2(__float_as_uint(bvr), (unsigned)bir);
}

// ---------------- kernel 3: reduce partials -> ids (f32 output) ----------------
__global__ void k_pick(const uint2* __restrict__ part, int* __restrict__ ids,
                       float* __restrict__ outIds) {
    int rr = blockIdx.x * blockDim.x + threadIdx.x;
    if (rr >= ROWS) return;
    float bvv = __uint_as_float(part[(size_t)rr * NSPLIT].x);
    int   bii = (int)part[(size_t)rr * NSPLIT].y;
    for (int cs2 = 1; cs2 < NSPLIT; ++cs2) {
        float v = __uint_as_float(part[(size_t)rr * NSPLIT + cs2].x);
        int   x = (int)part[(size_t)rr * NSPLIT + cs2].y;
        if (v < bvv || (v == bvv && x < bii)) { bvv = v; bii = x; }
    }
    bii = bii < 0 ? 0 : (bii > NCODES - 1 ? NCODES - 1 : bii);
    ids[rr] = bii;
    outIds[rr] = (float)bii;
}

// ---------------- kernel 4: gather z_q_st (f32) + loss partials ----------------
__global__ void k_gather(const float* __restrict__ zE, const float* __restrict__ cb,
                         const int* __restrict__ ids, float* __restrict__ outZ,
                         double* __restrict__ lossPart) {
    const int tid = threadIdx.x;
    double acc = 0.0;
#pragma unroll
    for (int it = 0; it < 4; ++it) {
        int chunk = blockIdx.x * 256 + tid + it * 1048576;   // float4 chunk id
        int row   = chunk >> 7;
        int koff  = (chunk & 127) << 2;
        int id    = ids[row];
        id = id < 0 ? 0 : (id > NCODES - 1 ? NCODES - 1 : id);
        float4 ze = *(const float4*)(zE + ((size_t)row << 9) + koff);
        float4 zq = *(const float4*)(cb + ((size_t)id << 9) + koff);
        float d0 = __fsub_rn(zq.x, ze.x);
        float d1 = __fsub_rn(zq.y, ze.y);
        float d2 = __fsub_rn(zq.z, ze.z);
        float d3 = __fsub_rn(zq.w, ze.w);
        float4 v;
        v.x = __fadd_rn(ze.x, d0);
        v.y = __fadd_rn(ze.y, d1);
        v.z = __fadd_rn(ze.z, d2);
        v.w = __fadd_rn(ze.w, d3);
        *reinterpret_cast<float4*>(outZ + ((size_t)chunk << 2)) = v;
        acc += (double)d0 * d0 + (double)d1 * d1 + (double)d2 * d2 + (double)d3 * d3;
    }
    for (int off = 32; off; off >>= 1) acc += __shfl_down(acc, off);
    __shared__ double sred[4];
    if ((tid & 63) == 0) sred[tid >> 6] = acc;
    __syncthreads();
    if (tid == 0) lossPart[blockIdx.x] = (sred[0] + sred[1]) + (sred[2] + sred[3]);
}

// ---------------- kernel 5: final loss (f32 output) ----------------
__global__ void k_loss(const double* __restrict__ lossPart, float* __restrict__ outLoss) {
    const int tid = threadIdx.x;
    double acc = 0.0;
    for (int i = tid; i < 4096; i += 256) acc += lossPart[i];
    for (int off = 32; off; off >>= 1) acc += __shfl_down(acc, off);
    __shared__ double sred[4];
    if ((tid & 63) == 0) sred[tid >> 6] = acc;
    __syncthreads();
    if (tid == 0) {
        double mean = ((sred[0] + sred[1]) + (sred[2] + sred[3])) / 16777216.0;
        float cl = (float)mean;
        *outLoss = __fadd_rn(cl, __fmul_rn(0.25f, cl));
    }
}

extern "C" void kernel_launch(void* const* d_in, const int* in_sizes, int n_in,
                              void* d_out, int out_size, void* d_ws, size_t ws_size,
                              hipStream_t stream) {
    (void)in_sizes; (void)n_in; (void)out_size; (void)ws_size;
    const float* zE = (const float*)d_in[0];
    const float* cb = (const float*)d_in[1];
    float* out = (float*)d_out;                    // f32 outputs, concatenated
    char* ws = (char*)d_ws;

    float*  sq       = (float*)(ws + 0);         // 32768 f32
    float*  e2       = (float*)(ws + 131072);    // 8192  f32
    int*    ids      = (int*)(ws + 163840);      // 32768 i32
    uint2*  part     = (uint2*)(ws + 294912);    // 32768*4 uint2 = 1 MiB
    double* lossPart = (double*)(ws + 1343488);  // 4096  f64

    k_rowsums<<<(ROWS + NCODES) / 64, 64, 0, stream>>>(zE, cb, sq, e2);
    dim3 g2(NSPLIT, ROWS / BM);
    k_argmin<<<g2, 512, 0, stream>>>(zE, cb, sq, e2, part);
    k_pick<<<ROWS / 256, 256, 0, stream>>>(part, ids, out + 16777216);
    k_gather<<<4096, 256, 0, stream>>>(zE, cb, ids, out, lossPart);
    k_loss<<<1, 256, 0, stream>>>(lossPart, out + 16777216 + 32768);
}